// Round 8
// baseline (243.284 us; speedup 1.0000x reference)
//
#include <hip/hip_runtime.h>
#include <hip/hip_bf16.h>
#include <cstdint>
#include <cstddef>

#define BB 2
#define NN 2048
#define CC 768
#define HH 12
#define DD 64
#define HID 3072
#define TT (BB*NN)   // 4096 tokens

typedef __attribute__((ext_vector_type(8))) short bf16x8;
typedef __attribute__((ext_vector_type(4))) short bf16x4;
typedef __attribute__((ext_vector_type(4))) float f32x4;

__device__ __forceinline__ unsigned short f2bf(float f) {
    unsigned int u = __float_as_uint(f);
    u += 0x7fffu + ((u >> 16) & 1u);
    return (unsigned short)(u >> 16);
}
__device__ __forceinline__ float bf2f(unsigned short u) {
    return __uint_as_float(((unsigned int)u) << 16);
}
#if __has_builtin(__builtin_amdgcn_exp2f)
#define EXP2F(x) __builtin_amdgcn_exp2f(x)
#else
#define EXP2F(x) exp2f(x)
#endif

// async global -> LDS, 16 bytes per lane (dest must be base + lane*16)
__device__ __forceinline__ void gload16(const void* g, void* l) {
    __builtin_amdgcn_global_load_lds((__attribute__((address_space(1))) unsigned int*)g,
                                     (__attribute__((address_space(3))) unsigned int*)l,
                                     16, 0, 0);
}

#define WAITV(N) asm volatile("s_waitcnt vmcnt(" #N ")" ::: "memory")
#define WAITLGKM asm volatile("s_waitcnt lgkmcnt(0)" ::: "memory")

// ---------------- fused fp32 -> bf16 convert (5 segments, vectorized) ----------------
struct CvtArgs {
    const float* in[5];
    unsigned short* out[5];
    int n4[5];   // element count / 4
};
typedef __attribute__((ext_vector_type(4))) float float4v;
typedef __attribute__((ext_vector_type(4))) unsigned short ushort4v;
__global__ __launch_bounds__(256) void cvt5_kernel(CvtArgs a) {
    int base = blockIdx.x * 256 + threadIdx.x;
    int stride = gridDim.x * 256;
#pragma unroll
    for (int s = 0; s < 5; ++s) {
        const float4v* ip = (const float4v*)a.in[s];
        ushort4v* op = (ushort4v*)a.out[s];
        for (int i = base; i < a.n4[s]; i += stride) {
            float4v v = ip[i];
            ushort4v o;
            o[0] = f2bf(v[0]); o[1] = f2bf(v[1]); o[2] = f2bf(v[2]); o[3] = f2bf(v[3]);
            op[i] = o;
        }
    }
}

// ---------------- mask -> bit pack (16 keys per ushort) ----------------
__global__ __launch_bounds__(256) void maskbits_kernel(const float* __restrict__ mask,
                                                       unsigned short* __restrict__ mb, int n) {
    int i = blockIdx.x * 256 + threadIdx.x;
    if (i >= n) return;
    const float4v* mp = (const float4v*)(mask + (size_t)i * 16);
    unsigned int bits = 0;
#pragma unroll
    for (int q = 0; q < 4; ++q) {
        float4v v = mp[q];
#pragma unroll
        for (int j = 0; j < 4; ++j) bits |= (v[j] > 0.5f) ? (1u << (q * 4 + j)) : 0u;
    }
    mb[i] = (unsigned short)bits;
}

// ---------------- LayerNorm (fp32 in, bf16 out), XCD-aligned token map ----------------
// token t = (block&7)*512 + block>>3  ->  XCD e (= block%8) processes tokens
// [e*512, (e+1)*512)  == the row-chunk the XCD-pinned GEMM consumer reads.
__global__ __launch_bounds__(256) void ln_kernel(const float* __restrict__ x,
                                                 const float* __restrict__ g,
                                                 const float* __restrict__ b,
                                                 unsigned short* __restrict__ out) {
    int t = ((blockIdx.x & 7) << 9) | (blockIdx.x >> 3);
    int tid = threadIdx.x;
    const float* xr = x + (size_t)t * CC;
    float v0 = xr[tid], v1 = xr[tid + 256], v2 = xr[tid + 512];
    float s = v0 + v1 + v2;
    float s2 = v0 * v0 + v1 * v1 + v2 * v2;
#pragma unroll
    for (int off = 1; off < 64; off <<= 1) {
        s  += __shfl_xor(s, off);
        s2 += __shfl_xor(s2, off);
    }
    __shared__ float red[8];
    int wv = tid >> 6, lane = tid & 63;
    if (lane == 0) { red[wv] = s; red[wv + 4] = s2; }
    __syncthreads();
    s  = red[0] + red[1] + red[2] + red[3];
    s2 = red[4] + red[5] + red[6] + red[7];
    float mu   = s * (1.0f / CC);
    float var  = s2 * (1.0f / CC) - mu * mu;
    float rstd = rsqrtf(var + 1e-5f);
    unsigned short* orow = out + (size_t)t * CC;
    orow[tid]       = f2bf((v0 - mu) * rstd * g[tid]       + b[tid]);
    orow[tid + 256] = f2bf((v1 - mu) * rstd * g[tid + 256] + b[tid + 256]);
    orow[tid + 512] = f2bf((v2 - mu) * rstd * g[tid + 512] + b[tid + 512]);
}

// ---------------- GEMM v6: BM=128 x BN=64, 24KB LDS, TLP-first ----------------
// C[M,N] = A[M,K..] @ Bw[N,K..]^T (+epilogue). BK=32, 2-stage dbuf, counted vmcnt.
// 4 waves stacked over M (wave = 32 rows x 64 cols = 2x4 fragments, 8 MFMA/iter).
// 24KB LDS -> 6 blocks/CU; grids are 1152-1536 blocks -> 20-24 waves/CU: latency
// hidden by wave multiplexing (m114), not per-wave pipelining (R5-R7 all flat).
// lda/ldb decoupled from K so fc2 can split-K (chunk len K, row stride lda).
// Swizzle: physical chunk p = lc ^ ((row>>1)&3) on GLOBAL source (linear LDS dest);
// fragment ds_read_b128 conflict-free (verified R5: conflicts = 0).
// Transposed acc (mfma(b,a)) -> vector f32x4/bf16x4 epilogue (exact write sizes).
// EPI 0: bf16; 1: +bias+res -> f32; 2: +bias+GELU -> bf16; 4: raw f32 (split-K part)
template <int EPI>
__global__ __launch_bounds__(256, 6) void gemm_bt(const unsigned short* __restrict__ A,
                                                  const unsigned short* __restrict__ Bw,
                                                  const float* __restrict__ bias,
                                                  const float* __restrict__ res,
                                                  void* __restrict__ out,
                                                  int M, int N, int lda, int ldb, int K) {
    __shared__ alignas(16) unsigned short As[2][128 * 32];   // 16 KB
    __shared__ alignas(16) unsigned short Bs[2][64 * 32];    // 8 KB
    int tid = threadIdx.x;
    int lane = tid & 63, wv = tid >> 6;
    int l16 = lane & 15, lg = lane >> 4;

    // XCD-pinned block remap (bijective; M/128 = 32, multiple of 8)
    int BMT = M >> 7, chunk = BMT >> 3;
    int id = blockIdx.x;
    int xcd = id & 7, r = id >> 3;
    int bm = xcd * chunk + (r % chunk);
    int bn = r / chunk;

    int wm = wv * 32;            // wave's M offset within tile

    const unsigned short* Ab = A + (size_t)bm * 128 * lda;
    const unsigned short* Bb = Bw + (size_t)bn * 64 * ldb;

    // staging: pre-swizzled global sources, linear LDS dests (rule #21)
    const unsigned short* aSrc[2]; int aDst[2];
#pragma unroll
    for (int i = 0; i < 2; ++i) {
        int c = tid + i * 256;                 // chunk in [0, 512)
        int row = c >> 2, p = c & 3;
        int lc = p ^ ((row >> 1) & 3);
        aSrc[i] = Ab + (size_t)row * lda + lc * 8;
        aDst[i] = c * 8;
    }
    const unsigned short* bSrc; int bDst;
    {
        int c = tid;                           // chunk in [0, 256)
        int row = c >> 2, p = c & 3;
        int lc = p ^ ((row >> 1) & 3);
        bSrc = Bb + (size_t)row * ldb + lc * 8;
        bDst = c * 8;
    }
    // fragment read offsets (swizzle invariant under +16 rows)
    int arow = wm + l16;
    int aoff = arow * 32 + ((lg ^ ((arow >> 1) & 3)) * 8);
    int boff = l16 * 32 + ((lg ^ ((l16 >> 1) & 3)) * 8);

    f32x4 acc[2][4];
#pragma unroll
    for (int i = 0; i < 2; ++i)
#pragma unroll
        for (int j = 0; j < 4; ++j) acc[i][j] = f32x4{0.f, 0.f, 0.f, 0.f};

    auto STAGE = [&](int s, int k0) {
#pragma unroll
        for (int i = 0; i < 2; ++i) gload16(aSrc[i] + k0, &As[s][aDst[i]]);
        gload16(bSrc + k0, &Bs[s][bDst]);
    };

    STAGE(0, 0);
    int nt = K / 32;
    for (int t = 0; t < nt; ++t) {
        int cur = t & 1;
        if (t + 1 < nt) {
            STAGE(cur ^ 1, (t + 1) * 32);
            WAITV(3);                          // tile t landed; t+1's 3 stay in flight
        } else {
            WAITV(0);
        }
        __builtin_amdgcn_s_barrier();
        bf16x8 af[2], bfr[4];
#pragma unroll
        for (int mi = 0; mi < 2; ++mi) af[mi]  = *(const bf16x8*)&As[cur][aoff + mi * 512];
#pragma unroll
        for (int ni = 0; ni < 4; ++ni)  bfr[ni] = *(const bf16x8*)&Bs[cur][boff + ni * 512];
#pragma unroll
        for (int mi = 0; mi < 2; ++mi)
#pragma unroll
            for (int ni = 0; ni < 4; ++ni)
                acc[mi][ni] = __builtin_amdgcn_mfma_f32_16x16x32_bf16(bfr[ni], af[mi], acc[mi][ni], 0, 0, 0);
        WAITLGKM;
        __builtin_amdgcn_s_barrier();
    }

    // vector epilogue: row = ...+l16, cols = base+lg*4+(0..3)
#pragma unroll
    for (int mi = 0; mi < 2; ++mi) {
        int row = bm * 128 + wm + mi * 16 + l16;
#pragma unroll
        for (int ni = 0; ni < 4; ++ni) {
            int col = bn * 64 + ni * 16 + lg * 4;
            size_t idx = (size_t)row * N + col;
            f32x4 v = acc[mi][ni];
            if (EPI == 0) {
                bf16x4 ov;
#pragma unroll
                for (int r2 = 0; r2 < 4; ++r2) ov[r2] = (short)f2bf(v[r2]);
                *(bf16x4*)((unsigned short*)out + idx) = ov;
            } else if (EPI == 1) {
                f32x4 bv = *(const f32x4*)&bias[col];
                f32x4 rv = *(const f32x4*)&res[idx];
                f32x4 ov;
#pragma unroll
                for (int r2 = 0; r2 < 4; ++r2) ov[r2] = v[r2] + bv[r2] + rv[r2];
                *(f32x4*)((float*)out + idx) = ov;
            } else if (EPI == 2) {
                f32x4 bv = *(const f32x4*)&bias[col];
                bf16x4 ov;
#pragma unroll
                for (int r2 = 0; r2 < 4; ++r2) {
                    float t2 = v[r2] + bv[r2];
                    t2 = 0.5f * t2 * (1.0f + erff(t2 * 0.70710678118f));
                    ov[r2] = (short)f2bf(t2);
                }
                *(bf16x4*)((unsigned short*)out + idx) = ov;
            } else {   // EPI 4: raw f32 partial
                *(f32x4*)((float*)out + idx) = v;
            }
        }
    }
}

// ---------------- split-K reduce: out += p1 + p2 (out already has p0+bias+res) ----
__global__ __launch_bounds__(256) void addred_kernel(float* __restrict__ out,
                                                     const float* __restrict__ p1,
                                                     const float* __restrict__ p2, int n4) {
    int i = blockIdx.x * 256 + threadIdx.x;
    int s = gridDim.x * 256;
    f32x4* o4 = (f32x4*)out;
    const f32x4* a4 = (const f32x4*)p1;
    const f32x4* b4 = (const f32x4*)p2;
    for (; i < n4; i += s) {
        f32x4 a = o4[i], b = a4[i], c = b4[i];
        f32x4 ov;
#pragma unroll
        for (int j = 0; j < 4; ++j) ov[j] = a[j] + b[j] + c[j];
        o4[i] = ov;
    }
}

// ---------------- Flash attention v5.1: XCD-pinned (b,h) (unchanged R7) ----------------
#define KVB 64
#define ANT (NN/KVB)   // 32 tiles
#define VP 68          // Vt pitch (ushorts)
__global__ __launch_bounds__(256, 4) void attn_kernel(const unsigned short* __restrict__ qkv,
                                                      const unsigned short* __restrict__ maskb,
                                                      unsigned short* __restrict__ o) {
    __shared__ alignas(16) unsigned short Ks[2][64 * 64];
    __shared__ alignas(16) unsigned short Vt[2][64 * VP];
    int tid = threadIdx.x;
    int lane = tid & 63, wv = tid >> 6;
    int l16 = lane & 15, lg = lane >> 4;
    int id = blockIdx.x;                 // 0..767
    int xcd = id & 7, r = id >> 3;       // r 0..95
    int bh = xcd * 3 + (r % 3);          // 0..23
    int qb = r / 3;                      // 0..31
    int b = bh / HH, h = bh % HH;
    int qrow = qb * 64 + wv * 16 + l16;

    const unsigned short* qp = qkv + ((size_t)(b * NN + qrow)) * 2304 + h * DD;
    bf16x8 q0r = *(const bf16x8*)(qp + 8 * lg);
    bf16x8 q1r = *(const bf16x8*)(qp + 32 + 8 * lg);
    const float QSC = 0.125f * 1.4426950408889634f;
    bf16x8 q0, q1;
#pragma unroll
    for (int j = 0; j < 8; ++j) {
        q0[j] = (short)f2bf(bf2f((unsigned short)q0r[j]) * QSC);
        q1[j] = (short)f2bf(bf2f((unsigned short)q1r[j]) * QSC);
    }

    const unsigned short* mrow  = maskb + ((size_t)(b * NN + qrow)) * 128;
    const unsigned short* kbase = qkv + (size_t)b * NN * 2304 + 768 + h * DD;
    const unsigned short* vbase = qkv + (size_t)b * NN * 2304 + 1536 + h * DD;

    const unsigned short* kSrc[2]; int kDst[2];
#pragma unroll
    for (int i = 0; i < 2; ++i) {
        int c = tid + i * 256;
        int row = c >> 3, p = c & 7;
        int lc = p ^ (row & 7);
        kSrc[i] = kbase + (size_t)row * 2304 + lc * 8;
        kDst[i] = c * 8;
    }
    int kp = tid & 31, dg = tid >> 5;
    const unsigned short* vSrc = vbase + (size_t)(2 * kp) * 2304 + dg * 8;

    int sw = l16 & 7;
    int kb0 = l16 * 64 + ((lg ^ sw) * 8);
    int kb1 = l16 * 64 + (((lg + 4) ^ sw) * 8);
    int vbo = l16 * VP + lg * 4;

    bf16x8 va, vb;
    unsigned long long mb_cur, mb_nxt;

    f32x4 oa[4];
#pragma unroll
    for (int i = 0; i < 4; ++i) oa[i] = f32x4{0.f, 0.f, 0.f, 0.f};
    float mrun = -INFINITY, lrun = 0.f;

    auto LOAD = [&](int t, int s) {
#pragma unroll
        for (int i = 0; i < 2; ++i) gload16(kSrc[i] + (size_t)t * KVB * 2304, &Ks[s][kDst[i]]);
        const unsigned short* vp = vSrc + (size_t)t * KVB * 2304;
        va = *(const bf16x8*)(vp);
        vb = *(const bf16x8*)(vp + 2304);
        mb_nxt = *(const unsigned long long*)(mrow + t * 4);
    };
    auto WRITEV = [&](int s) {
        unsigned int* VtU = (unsigned int*)Vt[s];
#pragma unroll
        for (int j = 0; j < 8; ++j)
            VtU[(dg * 8 + j) * (VP / 2) + kp] =
                (unsigned int)(unsigned short)va[j] | ((unsigned int)(unsigned short)vb[j] << 16);
    };

    LOAD(0, 0);
    WRITEV(0);
    mb_cur = mb_nxt;
    __syncthreads();
    int cur = 0;

    for (int kt = 0; kt < ANT; ++kt) {
        bool pre = (kt + 1 < ANT);
        if (pre) LOAD(kt + 1, cur ^ 1);
        const unsigned short* Ksc = Ks[cur];
        const unsigned short* Vtc = Vt[cur];

        float sv[16];
#pragma unroll
        for (int ks = 0; ks < 4; ++ks) {
            bf16x8 k0 = *(const bf16x8*)&Ksc[kb0 + ks * 1024];
            bf16x8 k1 = *(const bf16x8*)&Ksc[kb1 + ks * 1024];
            f32x4 sa = f32x4{0.f, 0.f, 0.f, 0.f};
            sa = __builtin_amdgcn_mfma_f32_16x16x32_bf16(k0, q0, sa, 0, 0, 0);
            sa = __builtin_amdgcn_mfma_f32_16x16x32_bf16(k1, q1, sa, 0, 0, 0);
            unsigned int m16 = (unsigned int)(mb_cur >> (ks * 16 + lg * 4));
#pragma unroll
            for (int r2 = 0; r2 < 4; ++r2) {
                float mbit = (float)((m16 >> r2) & 1u);
                sv[ks * 4 + r2] = fmaf(mbit, -144269.5f, sa[r2]);
            }
        }
        float tmax = sv[0];
#pragma unroll
        for (int i = 1; i < 16; ++i) tmax = fmaxf(tmax, sv[i]);
        tmax = fmaxf(tmax, __shfl_xor(tmax, 16));
        tmax = fmaxf(tmax, __shfl_xor(tmax, 32));

        if (__any(tmax > mrun + 11.5f)) {
            float mnew = fmaxf(mrun, tmax);
            float sc = EXP2F(mrun - mnew);
            lrun *= sc;
#pragma unroll
            for (int db = 0; db < 4; ++db) {
                oa[db][0] *= sc; oa[db][1] *= sc; oa[db][2] *= sc; oa[db][3] *= sc;
            }
            mrun = mnew;
        }

        float ps = 0.f;
        bf16x4 pf[4];
#pragma unroll
        for (int ks = 0; ks < 4; ++ks)
#pragma unroll
            for (int r2 = 0; r2 < 4; ++r2) {
                float p = EXP2F(sv[ks * 4 + r2] - mrun);
                ps += p;
                pf[ks][r2] = (short)f2bf(p);
            }
        lrun += ps;

#pragma unroll
        for (int ks = 0; ks < 4; ++ks)
#pragma unroll
            for (int db = 0; db < 4; ++db) {
                bf16x4 vf = *(const bf16x4*)&Vtc[vbo + db * 16 * VP + ks * 16];
                oa[db] = __builtin_amdgcn_mfma_f32_16x16x16bf16_1k(vf, pf[ks], oa[db], 0, 0, 0);
            }

        if (pre) WRITEV(cur ^ 1);
        __syncthreads();
        if (pre) { cur ^= 1; mb_cur = mb_nxt; }
    }

    float lt = lrun;
    lt += __shfl_xor(lt, 16);
    lt += __shfl_xor(lt, 32);
    float inv = 1.0f / lt;
    unsigned short* op = o + ((size_t)(b * NN + qrow)) * CC + h * DD;
#pragma unroll
    for (int db = 0; db < 4; ++db) {
        bf16x4 ov;
#pragma unroll
        for (int r2 = 0; r2 < 4; ++r2) ov[r2] = (short)f2bf(oa[db][r2] * inv);
        *(bf16x4*)&op[db * 16 + lg * 4] = ov;
    }
}

// ---------------- host launch ----------------
extern "C" void kernel_launch(void* const* d_in, const int* in_sizes, int n_in,
                              void* d_out, int out_size, void* d_ws, size_t ws_size,
                              hipStream_t stream) {
    const float* x    = (const float*)d_in[0];
    const float* mask = (const float*)d_in[1];
    const float* g1   = (const float*)d_in[2];
    const float* b1   = (const float*)d_in[3];
    const float* Wq   = (const float*)d_in[4];
    const float* Wkv  = (const float*)d_in[5];
    const float* Wp   = (const float*)d_in[6];
    const float* bp   = (const float*)d_in[7];
    const float* g2   = (const float*)d_in[8];
    const float* b2   = (const float*)d_in[9];
    const float* W1   = (const float*)d_in[10];
    const float* bf1  = (const float*)d_in[11];
    const float* W2   = (const float*)d_in[12];
    const float* bf2  = (const float*)d_in[13];
    float* out = (float*)d_out;

    char* w = (char*)d_ws;
    unsigned short* wqkv = (unsigned short*)w;      w += (size_t)2304 * 768 * 2;
    unsigned short* wp   = (unsigned short*)w;      w += (size_t)768 * 768 * 2;
    unsigned short* w1   = (unsigned short*)w;      w += (size_t)3072 * 768 * 2;
    unsigned short* w2   = (unsigned short*)w;      w += (size_t)768 * 3072 * 2;
    char* xn_region = w;                            // xn(6.29MB)+qkv(18.87MB) reused as fc2 partials
    unsigned short* xn   = (unsigned short*)w;      w += (size_t)TT * CC * 2;
    unsigned short* qkv  = (unsigned short*)w;      w += (size_t)TT * 2304 * 2;
    unsigned short* mb   = (unsigned short*)w;      w += (size_t)BB * NN * 128 * 2;
    unsigned short* obuf = (unsigned short*)w;      w += (size_t)TT * CC * 2;
    float*          x1   = (float*)w;               w += (size_t)TT * CC * 4;
    unsigned short* xn2  = (unsigned short*)w;      w += (size_t)TT * CC * 2;
    unsigned short* hbuf = (unsigned short*)w;      w += (size_t)TT * HID * 2;

    float* part1 = (float*)xn_region;                  // 12.58 MB
    float* part2 = part1 + (size_t)TT * CC;            // 12.58 MB (xn+qkv = 25.17 MB exactly)

    CvtArgs ca;
    ca.in[0] = Wq;  ca.out[0] = wqkv;             ca.n4[0] = 768 * 768 / 4;
    ca.in[1] = Wkv; ca.out[1] = wqkv + 768 * 768; ca.n4[1] = 1536 * 768 / 4;
    ca.in[2] = Wp;  ca.out[2] = wp;               ca.n4[2] = 768 * 768 / 4;
    ca.in[3] = W1;  ca.out[3] = w1;               ca.n4[3] = 3072 * 768 / 4;
    ca.in[4] = W2;  ca.out[4] = w2;               ca.n4[4] = 768 * 3072 / 4;
    cvt5_kernel<<<1024, 256, 0, stream>>>(ca);

    {
        int n = BB * NN * (NN / 16);
        maskbits_kernel<<<(n + 255) / 256, 256, 0, stream>>>(mask, mb, n);
    }

    ln_kernel<<<TT, 256, 0, stream>>>(x, g1, b1, xn);

    // qkv: M=4096 N=2304 K=768 -> grid 32*36 = 1152
    gemm_bt<0><<<32 * 36, 256, 0, stream>>>(xn, wqkv, nullptr, nullptr, qkv,
                                            TT, 2304, 768, 768, 768);

    attn_kernel<<<32 * 24, 256, 0, stream>>>(qkv, mb, obuf);

    // proj: M=4096 N=768 K=768 -> grid 32*12 = 384
    gemm_bt<1><<<32 * 12, 256, 0, stream>>>(obuf, wp, bp, x, x1,
                                            TT, 768, 768, 768, 768);

    ln_kernel<<<TT, 256, 0, stream>>>(x1, g2, b2, xn2);

    // fc1: M=4096 N=3072 K=768 -> grid 32*48 = 1536
    gemm_bt<2><<<32 * 48, 256, 0, stream>>>(xn2, w1, bf1, nullptr, hbuf,
                                            TT, HID, 768, 768, 768);

    // fc2 split-K x3 (K=3072 -> 3 x 1024), lda/ldb = 3072
    // p0: +bias+res -> d_out ; p1/p2: raw f32 partials
    gemm_bt<1><<<32 * 12, 256, 0, stream>>>(hbuf,        w2,        bf2, x1, out,
                                            TT, 768, 3072, 3072, 1024);
    gemm_bt<4><<<32 * 12, 256, 0, stream>>>(hbuf + 1024, w2 + 1024, nullptr, nullptr, part1,
                                            TT, 768, 3072, 3072, 1024);
    gemm_bt<4><<<32 * 12, 256, 0, stream>>>(hbuf + 2048, w2 + 2048, nullptr, nullptr, part2,
                                            TT, 768, 3072, 3072, 1024);
    addred_kernel<<<1024, 256, 0, stream>>>(out, part1, part2, TT * CC / 4);
}

// Round 9
// 216.689 us; speedup vs baseline: 1.1227x; 1.1227x over previous
//
#include <hip/hip_runtime.h>
#include <hip/hip_bf16.h>
#include <cstdint>
#include <cstddef>

#define BB 2
#define NN 2048
#define CC 768
#define HH 12
#define DD 64
#define HID 3072
#define TT (BB*NN)   // 4096 tokens

typedef __attribute__((ext_vector_type(8))) short bf16x8;
typedef __attribute__((ext_vector_type(4))) short bf16x4;
typedef __attribute__((ext_vector_type(4))) float f32x4;

__device__ __forceinline__ unsigned short f2bf(float f) {
    unsigned int u = __float_as_uint(f);
    u += 0x7fffu + ((u >> 16) & 1u);
    return (unsigned short)(u >> 16);
}
__device__ __forceinline__ float bf2f(unsigned short u) {
    return __uint_as_float(((unsigned int)u) << 16);
}
#if __has_builtin(__builtin_amdgcn_exp2f)
#define EXP2F(x) __builtin_amdgcn_exp2f(x)
#else
#define EXP2F(x) exp2f(x)
#endif

// async global -> LDS, 16 bytes per lane (dest must be base + lane*16)
__device__ __forceinline__ void gload16(const void* g, void* l) {
    __builtin_amdgcn_global_load_lds((__attribute__((address_space(1))) unsigned int*)g,
                                     (__attribute__((address_space(3))) unsigned int*)l,
                                     16, 0, 0);
}

#define WAITV(N) asm volatile("s_waitcnt vmcnt(" #N ")" ::: "memory")
#define WAITLGKM asm volatile("s_waitcnt lgkmcnt(0)" ::: "memory")

typedef __attribute__((ext_vector_type(4))) float float4v;
typedef __attribute__((ext_vector_type(4))) unsigned short ushort4v;

// ---------------- fused prep: LN1 (blocks 0..4095) + cvt (4096..5119) + maskbits (5120..6143) ----
struct PrepArgs {
    const float* x; const float* g1; const float* b1; unsigned short* xn;
    const float* cin[5]; unsigned short* cout[5]; int n4[5];
    const float* mask; unsigned short* mb;
};
__global__ __launch_bounds__(256) void prep_kernel(PrepArgs a) {
    int id = blockIdx.x;
    int tid = threadIdx.x;
    if (id < TT) {
        // ---- LayerNorm row id ----
        const float* xr = a.x + (size_t)id * CC;
        float v0 = xr[tid], v1 = xr[tid + 256], v2 = xr[tid + 512];
        float s = v0 + v1 + v2;
        float s2 = v0 * v0 + v1 * v1 + v2 * v2;
#pragma unroll
        for (int off = 1; off < 64; off <<= 1) {
            s  += __shfl_xor(s, off);
            s2 += __shfl_xor(s2, off);
        }
        __shared__ float red[8];
        int wv = tid >> 6, lane = tid & 63;
        if (lane == 0) { red[wv] = s; red[wv + 4] = s2; }
        __syncthreads();
        s  = red[0] + red[1] + red[2] + red[3];
        s2 = red[4] + red[5] + red[6] + red[7];
        float mu   = s * (1.0f / CC);
        float var  = s2 * (1.0f / CC) - mu * mu;
        float rstd = rsqrtf(var + 1e-5f);
        unsigned short* orow = a.xn + (size_t)id * CC;
        orow[tid]       = f2bf((v0 - mu) * rstd * a.g1[tid]       + a.b1[tid]);
        orow[tid + 256] = f2bf((v1 - mu) * rstd * a.g1[tid + 256] + a.b1[tid + 256]);
        orow[tid + 512] = f2bf((v2 - mu) * rstd * a.g1[tid + 512] + a.b1[tid + 512]);
    } else if (id < TT + 1024) {
        // ---- weight fp32->bf16 ----
        int base = (id - TT) * 256 + tid;
        int stride = 1024 * 256;
#pragma unroll
        for (int sseg = 0; sseg < 5; ++sseg) {
            const float4v* ip = (const float4v*)a.cin[sseg];
            ushort4v* op = (ushort4v*)a.cout[sseg];
            for (int i = base; i < a.n4[sseg]; i += stride) {
                float4v v = ip[i];
                ushort4v o;
                o[0] = f2bf(v[0]); o[1] = f2bf(v[1]); o[2] = f2bf(v[2]); o[3] = f2bf(v[3]);
                op[i] = o;
            }
        }
    } else {
        // ---- mask -> bitpack (16 keys per ushort) ----
        int base = (id - TT - 1024) * 256 + tid;
        int stride = 1024 * 256;
        int n = BB * NN * (NN / 16);
        for (int i = base; i < n; i += stride) {
            const float4v* mp = (const float4v*)(a.mask + (size_t)i * 16);
            unsigned int bits = 0;
#pragma unroll
            for (int q = 0; q < 4; ++q) {
                float4v v = mp[q];
#pragma unroll
                for (int j = 0; j < 4; ++j) bits |= (v[j] > 0.5f) ? (1u << (q * 4 + j)) : 0u;
            }
            a.mb[i] = (unsigned short)bits;
        }
    }
}

// ---------------- LayerNorm (standalone, for LN2) ----------------
__global__ __launch_bounds__(256) void ln_kernel(const float* __restrict__ x,
                                                 const float* __restrict__ g,
                                                 const float* __restrict__ b,
                                                 unsigned short* __restrict__ out) {
    int t = blockIdx.x;
    int tid = threadIdx.x;
    const float* xr = x + (size_t)t * CC;
    float v0 = xr[tid], v1 = xr[tid + 256], v2 = xr[tid + 512];
    float s = v0 + v1 + v2;
    float s2 = v0 * v0 + v1 * v1 + v2 * v2;
#pragma unroll
    for (int off = 1; off < 64; off <<= 1) {
        s  += __shfl_xor(s, off);
        s2 += __shfl_xor(s2, off);
    }
    __shared__ float red[8];
    int wv = tid >> 6, lane = tid & 63;
    if (lane == 0) { red[wv] = s; red[wv + 4] = s2; }
    __syncthreads();
    s  = red[0] + red[1] + red[2] + red[3];
    s2 = red[4] + red[5] + red[6] + red[7];
    float mu   = s * (1.0f / CC);
    float var  = s2 * (1.0f / CC) - mu * mu;
    float rstd = rsqrtf(var + 1e-5f);
    unsigned short* orow = out + (size_t)t * CC;
    orow[tid]       = f2bf((v0 - mu) * rstd * g[tid]       + b[tid]);
    orow[tid + 256] = f2bf((v1 - mu) * rstd * g[tid + 256] + b[tid + 256]);
    orow[tid + 512] = f2bf((v2 - mu) * rstd * g[tid + 512] + b[tid + 512]);
}

// ---------------- GEMM (R5 v3, best-known): dbuf + counted vmcnt + vector epilogue ----
// C[M,N] = A[M,K] @ Bw[N,K]^T (+epilogue). BK=32, BN=128.
// EPI 0: bf16; 1: +bias+res->f32; 2: +bias+GELU->bf16; 3: +bias+res->f32
template <int EPI, int BM>
__global__ __launch_bounds__(256) void gemm_bt(const unsigned short* __restrict__ A,
                                               const unsigned short* __restrict__ Bw,
                                               const float* __restrict__ bias,
                                               const float* __restrict__ res,
                                               void* __restrict__ out,
                                               int M, int N, int K) {
    constexpr int MI = BM / 32;           // 4 (BM=128) or 2 (BM=64)
    constexpr int NCA = (BM * 4) / 256;   // A chunks per thread: 2 or 1
    __shared__ alignas(16) unsigned short As[2][BM * 32];
    __shared__ alignas(16) unsigned short Bs[2][128 * 32];
    int tid = threadIdx.x;
    int lane = tid & 63, wv = tid >> 6;
    int l16 = lane & 15, lg = lane >> 4;
    int bm = blockIdx.x, bn = blockIdx.y;
    int wm = (wv & 1) * (BM / 2), wn = (wv >> 1) * 64;

    const unsigned short* Ab = A + (size_t)bm * BM * K;
    const unsigned short* Bb = Bw + (size_t)bn * 128 * K;

    // staging: pre-swizzled global sources, linear LDS dests (rule #21)
    const unsigned short* aSrc[NCA]; int aDst[NCA];
#pragma unroll
    for (int i = 0; i < NCA; ++i) {
        int c = tid + i * 256;
        int row = c >> 2, p = c & 3;
        int lc = p ^ ((row >> 1) & 3);
        aSrc[i] = Ab + (size_t)row * K + lc * 8;
        aDst[i] = c * 8;
    }
    const unsigned short* bSrc[2]; int bDst[2];
#pragma unroll
    for (int i = 0; i < 2; ++i) {
        int c = tid + i * 256;
        int row = c >> 2, p = c & 3;
        int lc = p ^ ((row >> 1) & 3);
        bSrc[i] = Bb + (size_t)row * K + lc * 8;
        bDst[i] = c * 8;
    }
    // fragment read offsets (swizzle term invariant under +16 rows)
    int aoff = (wm + l16) * 32 + ((lg ^ (((wm + l16) >> 1) & 3)) * 8);
    int boff = (wn + l16) * 32 + ((lg ^ (((wn + l16) >> 1) & 3)) * 8);

    f32x4 acc[MI][4];
#pragma unroll
    for (int i = 0; i < MI; ++i)
#pragma unroll
        for (int j = 0; j < 4; ++j) acc[i][j] = f32x4{0.f, 0.f, 0.f, 0.f};

    auto STAGE = [&](int s, int k0) {
#pragma unroll
        for (int i = 0; i < NCA; ++i) gload16(aSrc[i] + k0, &As[s][aDst[i]]);
#pragma unroll
        for (int i = 0; i < 2; ++i)   gload16(bSrc[i] + k0, &Bs[s][bDst[i]]);
    };

    STAGE(0, 0);
    int nt = K / 32;
    for (int t = 0; t < nt; ++t) {
        int cur = t & 1;
        if (t + 1 < nt) {
            STAGE(cur ^ 1, (t + 1) * 32);
            if constexpr (NCA + 2 == 4) { WAITV(4); } else { WAITV(3); }
        } else {
            WAITV(0);
        }
        __builtin_amdgcn_s_barrier();
        bf16x8 af[MI], bfr[4];
#pragma unroll
        for (int mi = 0; mi < MI; ++mi) af[mi]  = *(const bf16x8*)&As[cur][aoff + mi * 512];
#pragma unroll
        for (int ni = 0; ni < 4; ++ni)  bfr[ni] = *(const bf16x8*)&Bs[cur][boff + ni * 512];
#pragma unroll
        for (int mi = 0; mi < MI; ++mi)
#pragma unroll
            for (int ni = 0; ni < 4; ++ni)
                acc[mi][ni] = __builtin_amdgcn_mfma_f32_16x16x32_bf16(bfr[ni], af[mi], acc[mi][ni], 0, 0, 0);
        WAITLGKM;
        __builtin_amdgcn_s_barrier();
    }

    // vector epilogue: row = ...+l16, cols = base+lg*4+(0..3)
#pragma unroll
    for (int mi = 0; mi < MI; ++mi) {
        int row = bm * BM + wm + mi * 16 + l16;
#pragma unroll
        for (int ni = 0; ni < 4; ++ni) {
            int col = bn * 128 + wn + ni * 16 + lg * 4;
            size_t idx = (size_t)row * N + col;
            f32x4 v = acc[mi][ni];
            if (EPI == 0) {
                bf16x4 ov;
#pragma unroll
                for (int r2 = 0; r2 < 4; ++r2) ov[r2] = (short)f2bf(v[r2]);
                *(bf16x4*)((unsigned short*)out + idx) = ov;
            } else if (EPI == 1 || EPI == 3) {
                f32x4 bv = *(const f32x4*)&bias[col];
                f32x4 rv = *(const f32x4*)&res[idx];
                f32x4 ov;
#pragma unroll
                for (int r2 = 0; r2 < 4; ++r2) ov[r2] = v[r2] + bv[r2] + rv[r2];
                *(f32x4*)((float*)out + idx) = ov;
            } else {
                f32x4 bv = *(const f32x4*)&bias[col];
                bf16x4 ov;
#pragma unroll
                for (int r2 = 0; r2 < 4; ++r2) {
                    float t2 = v[r2] + bv[r2];
                    t2 = 0.5f * t2 * (1.0f + erff(t2 * 0.70710678118f));
                    ov[r2] = (short)f2bf(t2);
                }
                *(bf16x4*)((unsigned short*)out + idx) = ov;
            }
        }
    }
}

// ---------------- Flash attention v6: NO min-waves clamp (spill fix), XCD-pinned ----
#define KVB 64
#define ANT (NN/KVB)   // 32 tiles
#define VP 68          // Vt pitch (ushorts)
__global__ __launch_bounds__(256) void attn_kernel(const unsigned short* __restrict__ qkv,
                                                   const unsigned short* __restrict__ maskb,
                                                   unsigned short* __restrict__ o) {
    __shared__ alignas(16) unsigned short Ks[2][64 * 64];
    __shared__ alignas(16) unsigned short Vt[2][64 * VP];
    int tid = threadIdx.x;
    int lane = tid & 63, wv = tid >> 6;
    int l16 = lane & 15, lg = lane >> 4;
    int id = blockIdx.x;                 // 0..767
    int xcd = id & 7, r = id >> 3;       // r 0..95
    int bh = xcd * 3 + (r % 3);          // 0..23
    int qb = r / 3;                      // 0..31
    int b = bh / HH, h = bh % HH;
    int qrow = qb * 64 + wv * 16 + l16;

    const unsigned short* qp = qkv + ((size_t)(b * NN + qrow)) * 2304 + h * DD;
    bf16x8 q0r = *(const bf16x8*)(qp + 8 * lg);
    bf16x8 q1r = *(const bf16x8*)(qp + 32 + 8 * lg);
    const float QSC = 0.125f * 1.4426950408889634f;
    bf16x8 q0, q1;
#pragma unroll
    for (int j = 0; j < 8; ++j) {
        q0[j] = (short)f2bf(bf2f((unsigned short)q0r[j]) * QSC);
        q1[j] = (short)f2bf(bf2f((unsigned short)q1r[j]) * QSC);
    }

    const unsigned short* mrow  = maskb + ((size_t)(b * NN + qrow)) * 128;
    const unsigned short* kbase = qkv + (size_t)b * NN * 2304 + 768 + h * DD;
    const unsigned short* vbase = qkv + (size_t)b * NN * 2304 + 1536 + h * DD;

    const unsigned short* kSrc[2]; int kDst[2];
#pragma unroll
    for (int i = 0; i < 2; ++i) {
        int c = tid + i * 256;
        int row = c >> 3, p = c & 7;
        int lc = p ^ (row & 7);
        kSrc[i] = kbase + (size_t)row * 2304 + lc * 8;
        kDst[i] = c * 8;
    }
    int kp = tid & 31, dg = tid >> 5;
    const unsigned short* vSrc = vbase + (size_t)(2 * kp) * 2304 + dg * 8;

    int sw = l16 & 7;
    int kb0 = l16 * 64 + ((lg ^ sw) * 8);
    int kb1 = l16 * 64 + (((lg + 4) ^ sw) * 8);
    int vbo = l16 * VP + lg * 4;

    bf16x8 va, vb;
    unsigned long long mb_cur, mb_nxt;

    f32x4 oa[4];
#pragma unroll
    for (int i = 0; i < 4; ++i) oa[i] = f32x4{0.f, 0.f, 0.f, 0.f};
    float mrun = -INFINITY, lrun = 0.f;

    auto LOAD = [&](int t, int s) {
#pragma unroll
        for (int i = 0; i < 2; ++i) gload16(kSrc[i] + (size_t)t * KVB * 2304, &Ks[s][kDst[i]]);
        const unsigned short* vp = vSrc + (size_t)t * KVB * 2304;
        va = *(const bf16x8*)(vp);
        vb = *(const bf16x8*)(vp + 2304);
        mb_nxt = *(const unsigned long long*)(mrow + t * 4);
    };
    auto WRITEV = [&](int s) {
        unsigned int* VtU = (unsigned int*)Vt[s];
#pragma unroll
        for (int j = 0; j < 8; ++j)
            VtU[(dg * 8 + j) * (VP / 2) + kp] =
                (unsigned int)(unsigned short)va[j] | ((unsigned int)(unsigned short)vb[j] << 16);
    };

    LOAD(0, 0);
    WRITEV(0);
    mb_cur = mb_nxt;
    __syncthreads();
    int cur = 0;

    for (int kt = 0; kt < ANT; ++kt) {
        bool pre = (kt + 1 < ANT);
        if (pre) LOAD(kt + 1, cur ^ 1);
        const unsigned short* Ksc = Ks[cur];
        const unsigned short* Vtc = Vt[cur];

        float sv[16];
#pragma unroll
        for (int ks = 0; ks < 4; ++ks) {
            bf16x8 k0 = *(const bf16x8*)&Ksc[kb0 + ks * 1024];
            bf16x8 k1 = *(const bf16x8*)&Ksc[kb1 + ks * 1024];
            f32x4 sa = f32x4{0.f, 0.f, 0.f, 0.f};
            sa = __builtin_amdgcn_mfma_f32_16x16x32_bf16(k0, q0, sa, 0, 0, 0);
            sa = __builtin_amdgcn_mfma_f32_16x16x32_bf16(k1, q1, sa, 0, 0, 0);
            unsigned int m16 = (unsigned int)(mb_cur >> (ks * 16 + lg * 4));
#pragma unroll
            for (int r2 = 0; r2 < 4; ++r2) {
                float mbit = (float)((m16 >> r2) & 1u);
                sv[ks * 4 + r2] = fmaf(mbit, -144269.5f, sa[r2]);
            }
        }
        float tmax = sv[0];
#pragma unroll
        for (int i = 1; i < 16; ++i) tmax = fmaxf(tmax, sv[i]);
        tmax = fmaxf(tmax, __shfl_xor(tmax, 16));
        tmax = fmaxf(tmax, __shfl_xor(tmax, 32));

        if (__any(tmax > mrun + 11.5f)) {
            float mnew = fmaxf(mrun, tmax);
            float sc = EXP2F(mrun - mnew);
            lrun *= sc;
#pragma unroll
            for (int db = 0; db < 4; ++db) {
                oa[db][0] *= sc; oa[db][1] *= sc; oa[db][2] *= sc; oa[db][3] *= sc;
            }
            mrun = mnew;
        }

        float ps = 0.f;
        bf16x4 pf[4];
#pragma unroll
        for (int ks = 0; ks < 4; ++ks)
#pragma unroll
            for (int r2 = 0; r2 < 4; ++r2) {
                float p = EXP2F(sv[ks * 4 + r2] - mrun);
                ps += p;
                pf[ks][r2] = (short)(__float_as_uint(p) >> 16);   // truncating bf16 (P>=0)
            }
        lrun += ps;

#pragma unroll
        for (int ks = 0; ks < 4; ++ks)
#pragma unroll
            for (int db = 0; db < 4; ++db) {
                bf16x4 vf = *(const bf16x4*)&Vtc[vbo + db * 16 * VP + ks * 16];
                oa[db] = __builtin_amdgcn_mfma_f32_16x16x16bf16_1k(vf, pf[ks], oa[db], 0, 0, 0);
            }

        if (pre) WRITEV(cur ^ 1);
        __syncthreads();
        if (pre) { cur ^= 1; mb_cur = mb_nxt; }
    }

    float lt = lrun;
    lt += __shfl_xor(lt, 16);
    lt += __shfl_xor(lt, 32);
    float inv = 1.0f / lt;
    unsigned short* op = o + ((size_t)(b * NN + qrow)) * CC + h * DD;
#pragma unroll
    for (int db = 0; db < 4; ++db) {
        bf16x4 ov;
#pragma unroll
        for (int r2 = 0; r2 < 4; ++r2) ov[r2] = (short)f2bf(oa[db][r2] * inv);
        *(bf16x4*)&op[db * 16 + lg * 4] = ov;
    }
}

// ---------------- host launch ----------------
extern "C" void kernel_launch(void* const* d_in, const int* in_sizes, int n_in,
                              void* d_out, int out_size, void* d_ws, size_t ws_size,
                              hipStream_t stream) {
    const float* x    = (const float*)d_in[0];
    const float* mask = (const float*)d_in[1];
    const float* g1   = (const float*)d_in[2];
    const float* b1   = (const float*)d_in[3];
    const float* Wq   = (const float*)d_in[4];
    const float* Wkv  = (const float*)d_in[5];
    const float* Wp   = (const float*)d_in[6];
    const float* bp   = (const float*)d_in[7];
    const float* g2   = (const float*)d_in[8];
    const float* b2   = (const float*)d_in[9];
    const float* W1   = (const float*)d_in[10];
    const float* bf1  = (const float*)d_in[11];
    const float* W2   = (const float*)d_in[12];
    const float* bf2  = (const float*)d_in[13];
    float* out = (float*)d_out;

    char* w = (char*)d_ws;
    unsigned short* wqkv = (unsigned short*)w;      w += (size_t)2304 * 768 * 2;
    unsigned short* wp   = (unsigned short*)w;      w += (size_t)768 * 768 * 2;
    unsigned short* w1   = (unsigned short*)w;      w += (size_t)3072 * 768 * 2;
    unsigned short* w2   = (unsigned short*)w;      w += (size_t)768 * 3072 * 2;
    unsigned short* xn   = (unsigned short*)w;      w += (size_t)TT * CC * 2;
    unsigned short* qkv  = (unsigned short*)w;      w += (size_t)TT * 2304 * 2;
    unsigned short* mb   = (unsigned short*)w;      w += (size_t)BB * NN * 128 * 2;
    unsigned short* obuf = (unsigned short*)w;      w += (size_t)TT * CC * 2;
    float*          x1   = (float*)w;               w += (size_t)TT * CC * 4;
    unsigned short* xn2  = (unsigned short*)w;      w += (size_t)TT * CC * 2;
    unsigned short* hbuf = (unsigned short*)w;      w += (size_t)TT * HID * 2;

    PrepArgs pa;
    pa.x = x; pa.g1 = g1; pa.b1 = b1; pa.xn = xn;
    pa.cin[0] = Wq;  pa.cout[0] = wqkv;             pa.n4[0] = 768 * 768 / 4;
    pa.cin[1] = Wkv; pa.cout[1] = wqkv + 768 * 768; pa.n4[1] = 1536 * 768 / 4;
    pa.cin[2] = Wp;  pa.cout[2] = wp;               pa.n4[2] = 768 * 768 / 4;
    pa.cin[3] = W1;  pa.cout[3] = w1;               pa.n4[3] = 3072 * 768 / 4;
    pa.cin[4] = W2;  pa.cout[4] = w2;               pa.n4[4] = 768 * 3072 / 4;
    pa.mask = mask; pa.mb = mb;
    prep_kernel<<<TT + 2048, 256, 0, stream>>>(pa);

    // qkv: M=4096 N=2304 K=768
    gemm_bt<0, 128><<<dim3(TT / 128, 2304 / 128), 256, 0, stream>>>(xn, wqkv, nullptr, nullptr, qkv, TT, 2304, 768);

    attn_kernel<<<32 * 24, 256, 0, stream>>>(qkv, mb, obuf);

    // proj: M=4096 N=768 K=768
    gemm_bt<1, 64><<<dim3(TT / 64, 768 / 128), 256, 0, stream>>>(obuf, wp, bp, x, x1, TT, 768, 768);

    ln_kernel<<<TT, 256, 0, stream>>>(x1, g2, b2, xn2);

    // fc1: M=4096 N=3072 K=768
    gemm_bt<2, 128><<<dim3(TT / 128, HID / 128), 256, 0, stream>>>(xn2, w1, bf1, nullptr, hbuf, TT, HID, 768);

    // fc2: M=4096 N=768 K=3072
    gemm_bt<3, 64><<<dim3(TT / 64, 768 / 128), 256, 0, stream>>>(hbuf, w2, bf2, x1, out, TT, 768, HID);
}